// Round 5
// baseline (959.183 us; speedup 1.0000x reference)
//
#include <hip/hip_runtime.h>
#include <hip/hip_bf16.h>

// ---------------- problem constants ----------------
#define T_TOK 8192          // B*S tokens
#define D_DIM 1024
#define F_DIM 2048
#define E_NUM 8
#define NPAIR (T_TOK*2)     // 16384 token-expert pairs (top-2)
#define MAX_TILES 264       // >= NPAIR/64 + E_NUM (covers bmStep=64 fallback)
#define LDA 72              // padded LDS row stride (bf16 elems)

// ---------------- compact ws layout (bytes) ----------------
// meta ints: [0..7]=counts, [8..15]=cursors, [16..24]=seg offs, [25]=ntiles, [26]=f32flag
#define META_OFF   0ULL
#define TILE_OFF   4096ULL       // int4 * 264
#define RIDX_OFF   12288ULL      // int  [T*2]
#define RW_OFF     77824ULL      // f32  [T*2]
#define PT_OFF     143360ULL     // int  [NPAIR]
#define PW_OFF     208896ULL     // f32  [NPAIR]
#define DYN_OFF    524288ULL     // Xb / Wb / H packed here depending on ws_size

typedef __bf16 bf16_8 __attribute__((ext_vector_type(8)));
typedef float  f32_4  __attribute__((ext_vector_type(4)));

__device__ __forceinline__ float bf2f(unsigned short u) {
    union { unsigned u32; float f; } v; v.u32 = ((unsigned)u) << 16; return v.f;
}
__device__ __forceinline__ unsigned short f2bf(float f) {
    union { float f; unsigned u; } v; v.f = f;
    unsigned u = v.u;
    unsigned r = (u + 0x7FFFu + ((u >> 16) & 1u)) >> 16;   // RNE
    return (unsigned short)r;
}
__device__ __forceinline__ int iclamp(int v, int lo, int hi) {
    return v < lo ? lo : (v > hi ? hi : v);
}
// load 8 consecutive elements (element index ei, multiple of 8) as 8 packed bf16
__device__ __forceinline__ uint4 load8(const void* base, size_t ei, int f32) {
    if (f32) {
        const float* p = (const float*)base + ei;
        uint4 a = *(const uint4*)p;
        uint4 b = *(const uint4*)(p + 4);
        const float* fa = (const float*)&a;
        const float* fb = (const float*)&b;
        uint4 r;
        unsigned short* s = (unsigned short*)&r;
#pragma unroll
        for (int j = 0; j < 4; j++) { s[j] = f2bf(fa[j]); s[4+j] = f2bf(fb[j]); }
        return r;
    }
    return *(const uint4*)((const unsigned short*)base + ei);
}
__device__ __forceinline__ float loadf(const void* base, size_t ei, int f32) {
    return f32 ? ((const float*)base)[ei] : bf2f(((const unsigned short*)base)[ei]);
}
__device__ __forceinline__ void load8f(const void* base, size_t ei, int f32, float* o) {
    if (f32) {
        const float* p = (const float*)base + ei;
        uint4 a = *(const uint4*)p;
        uint4 b = *(const uint4*)(p + 4);
        const float* fa = (const float*)&a;
        const float* fb = (const float*)&b;
#pragma unroll
        for (int j = 0; j < 4; j++) { o[j] = fa[j]; o[4+j] = fb[j]; }
    } else {
        uint4 r = *(const uint4*)((const unsigned short*)base + ei);
        const unsigned short* s = (const unsigned short*)&r;
#pragma unroll
        for (int j = 0; j < 8; j++) o[j] = bf2f(s[j]);
    }
}

// ---------------- zero meta ----------------
__global__ void k_zero(int* __restrict__ p)
{
    p[blockIdx.x * 256 + threadIdx.x] = 0;    // <<<4,256>>>
}

// ---------------- zero output (f32, accumulated via atomicAdd) ----------------
// NOTE: out_size from the harness is the f32 ELEMENT count (8192*1024), not bytes.
// Output extent is a compile-time constant; zero exactly T_TOK*D_DIM floats = 32 MB.
__global__ __launch_bounds__(256) void k_zero_out(uint4* __restrict__ p)
{
    p[(size_t)blockIdx.x * 256 + threadIdx.x] = make_uint4(0,0,0,0);  // <<<8192,256>>>
}

// ---------------- dtype detect: meta[26] = 1 if inputs are float32 ----------------
__global__ void k_dtype(const unsigned* __restrict__ x, int* __restrict__ meta)
{
    if (threadIdx.x == 0 && blockIdx.x == 0) {
        int cnt = 0;
        for (int i = 0; i < 64; i++) {
            unsigned w = x[i];
            int e = (int)((w >> 7) & 0xffu);
            cnt += (e >= 118 && e <= 136) ? 1 : 0;
        }
        meta[26] = (cnt < 32) ? 1 : 0;
    }
}

// ---------------- one-time X -> bf16 ----------------
__global__ __launch_bounds__(256) void k_cvt_x(const void* __restrict__ x,
                                               unsigned short* __restrict__ xb,
                                               const int* __restrict__ meta)
{
    int fl = meta[26];
    size_t i = ((size_t)blockIdx.x * 256 + threadIdx.x) * 8;   // <<<T*D/2048,256>>>
    uint4 v = load8(x, i, fl);
    *(uint4*)&xb[i] = v;
}

// ---------------- one-time weight convert + transpose ----------------
// src: [E][R][C] (f32 or bf16)  ->  dst: [E][C][R] bf16
__global__ __launch_bounds__(256) void k_cvt_t(const void* __restrict__ src,
                                               unsigned short* __restrict__ dst,
                                               const int* __restrict__ meta,
                                               int R, int C)
{
    __shared__ unsigned short L[64 * 72];
    int fl = meta[26];
    int tilesC = C >> 6;
    int tilesR = R >> 6;
    int per = tilesR * tilesC;
    int e   = blockIdx.x / per;
    int rem = blockIdx.x % per;
    int rt = rem / tilesC, ct = rem % tilesC;
    int tid = threadIdx.x;
    // phase 1: read 64(r) x 64(c) tile coalesced, store transposed into LDS
    int rr = tid >> 2;
    int cc = (tid & 3) * 16;
    size_t so = (size_t)e * R * C + (size_t)(rt * 64 + rr) * C + (size_t)(ct * 64 + cc);
    float v[16];
    load8f(src, so, fl, v);
    load8f(src, so + 8, fl, v + 8);
#pragma unroll
    for (int j = 0; j < 16; j++) L[(cc + j) * 72 + rr] = f2bf(v[j]);
    __syncthreads();
    // phase 2: write out coalesced rows of dst (row = c, cols = r)
    int cr = tid >> 2;
    int rc = (tid & 3) * 16;
    uint4 o0 = *(const uint4*)&L[cr * 72 + rc];
    uint4 o1 = *(const uint4*)&L[cr * 72 + rc + 8];
    size_t dbo = (size_t)e * C * R + (size_t)(ct * 64 + cr) * R + (size_t)(rt * 64 + rc);
    *(uint4*)&dst[dbo]     = o0;
    *(uint4*)&dst[dbo + 8] = o1;
}

// ---------------- router (full f32 precision) ----------------
__global__ __launch_bounds__(256) void k_router(const void* __restrict__ x,
                                                const void* __restrict__ wg,
                                                int* __restrict__ meta,
                                                int* __restrict__ ridx,
                                                float* __restrict__ rw)
{
    int lane = threadIdx.x & 63;
    int wv   = threadIdx.x >> 6;
    int t    = blockIdx.x * 4 + wv;
    int fl   = meta[26];
    float acc[E_NUM];
#pragma unroll
    for (int e = 0; e < E_NUM; e++) acc[e] = 0.f;
    for (int d = lane; d < D_DIM; d += 64) {
        float xv = loadf(x, (size_t)t * D_DIM + d, fl);
        float wr[E_NUM];
        load8f(wg, (size_t)d * E_NUM, fl, wr);
#pragma unroll
        for (int e = 0; e < E_NUM; e++) acc[e] += xv * wr[e];
    }
#pragma unroll
    for (int off = 32; off > 0; off >>= 1)
#pragma unroll
        for (int e = 0; e < E_NUM; e++) acc[e] += __shfl_xor(acc[e], off, 64);

    if (lane == 0) {
        int i0 = 0; float m0v = acc[0];
        for (int e = 1; e < E_NUM; e++) if (acc[e] > m0v) { m0v = acc[e]; i0 = e; }
        int i1 = (i0 == 0) ? 1 : 0; float m1v = acc[i1];
        for (int e = 0; e < E_NUM; e++) if (e != i0 && acc[e] > m1v) { m1v = acc[e]; i1 = e; }
        float e1 = __expf(m1v - m0v);
        float w0 = 1.f / (1.f + e1);
        ridx[2*t] = i0; ridx[2*t+1] = i1;
        rw[2*t] = w0;   rw[2*t+1] = 1.f - w0;
        atomicAdd(&meta[i0], 1);
        atomicAdd(&meta[i1], 1);
    }
}

// ---------------- setup (tile step is runtime: 128 normal, 64 tiny-ws fallback) ----------------
__global__ void k_setup(int* __restrict__ meta, int4* __restrict__ tiles, int bmStep)
{
    if (threadIdx.x == 0 && blockIdx.x == 0) {
        int seg = 0, nt = 0;
        for (int e = 0; e < E_NUM; e++) {
            int c = meta[e]; c = iclamp(c, 0, NPAIR);
            meta[16 + e] = seg;
            meta[8 + e]  = seg;
            for (int m0 = 0; m0 < c && nt < MAX_TILES; m0 += bmStep) {
                int r = c - m0; if (r > bmStep) r = bmStep;
                tiles[nt++] = make_int4(seg + m0, e, r, 0);
            }
            seg += c;
        }
        meta[24] = seg;
        meta[25] = nt;
    }
}

// ---------------- scatter ----------------
__global__ __launch_bounds__(256) void k_scatter(const int* __restrict__ ridx,
                                                 const float* __restrict__ rw,
                                                 int* __restrict__ meta,
                                                 int* __restrict__ pt,
                                                 float* __restrict__ pw)
{
    __shared__ int lh[E_NUM];
    __shared__ int lbase[E_NUM];
    int tid = threadIdx.x;
    if (tid < E_NUM) lh[tid] = 0;
    __syncthreads();
    int t  = blockIdx.x * 256 + tid;
    int e0 = iclamp(ridx[2*t], 0, E_NUM-1);
    int e1 = iclamp(ridx[2*t+1], 0, E_NUM-1);
    int p0 = atomicAdd(&lh[e0], 1);
    int p1 = atomicAdd(&lh[e1], 1);
    __syncthreads();
    if (tid < E_NUM) lbase[tid] = atomicAdd(&meta[8 + tid], lh[tid]);
    __syncthreads();
    int pos0 = iclamp(lbase[e0] + p0, 0, NPAIR-1);
    int pos1 = iclamp(lbase[e1] + p1, 0, NPAIR-1);
    pt[pos0] = t; pw[pos0] = rw[2*t];
    pt[pos1] = t; pw[pos1] = rw[2*t+1];
}

// ---------------- GEMM1: H = silu(X*W1) .* (X*W3)  (BM=128, BN=64, BK=64) ----------------
// wb=1: b1p/b3p are bf16 pre-transposed [E][F][D].  wb=0: original [E][D][F] (fl dtype).
// xb=1: xs is bf16 [T][D].                          xb=0: xs is original x (fl dtype).
__global__ __launch_bounds__(256) void k_gemm1(const void* __restrict__ xs,
                                               const void* __restrict__ b1p,
                                               const void* __restrict__ b3p,
                                               const int*  __restrict__ meta,
                                               const int4* __restrict__ tiles,
                                               const int*  __restrict__ pt,
                                               unsigned short* __restrict__ H,
                                               int cbase, int clen, int xb, int wb, int hslop)
{
    __shared__ unsigned short As [128 * LDA];
    __shared__ unsigned short B1s[64 * LDA];
    __shared__ unsigned short B3s[64 * LDA];
    int nt = iclamp(meta[25], 0, MAX_TILES);
    if ((int)blockIdx.x >= nt) return;
    int4 td = tiles[blockIdx.x];
    if (td.x < cbase || td.x >= cbase + clen) return;
    int fl   = meta[26];
    int axfl = xb ? 0 : fl;
    int base = iclamp(td.x, 0, NPAIR-1);
    int e    = iclamp(td.y, 0, E_NUM-1);
    int rows = iclamp(td.z, 1, 128);
    if (base + rows > NPAIR) rows = NPAIR - base;
    int hrows = clen + hslop;
    int lbase_r = base - cbase;
    int f0 = blockIdx.y * 64;
    int tid = threadIdx.x, lane = tid & 63, wv = tid >> 6;

    // A staging: 128 rows x 64 k, 2 threads/row, 32 elems each
    int arow = tid >> 1;
    int acol = (tid & 1) * 32;
    int ar   = arow < rows ? arow : rows - 1;
    int atok = iclamp(pt[base + ar], 0, T_TOK-1);
    size_t abase = (size_t)atok * D_DIM + acol;

    // B staging (fast, pre-transposed [E][F][D]): 2 threads/f-row, 32 elems each
    int bu  = tid & 127;
    const void* bsrc = (tid < 128) ? b1p : b3p;
    unsigned short* bdst = (tid < 128) ? B1s : B3s;
    int bfr = bu >> 1;
    int bdc = (bu & 1) * 32;
    size_t bbT = (size_t)e * F_DIM * D_DIM + (size_t)(f0 + bfr) * D_DIM + (size_t)bdc;
    // B staging (slow, original [E][D][F]): 4 d-rows x 8 f each, transpose scatter
    int bd0 = (bu & 15) * 4;
    int bf0 = (bu >> 4) * 8;
    size_t bbS = (size_t)e * D_DIM * F_DIM + (size_t)(f0 + bf0);

    f32_4 acc1[2][4], acc3[2][4];
#pragma unroll
    for (int m = 0; m < 2; m++)
#pragma unroll
        for (int nn = 0; nn < 4; nn++) { acc1[m][nn] = 0.f; acc3[m][nn] = 0.f; }

    for (int k0 = 0; k0 < D_DIM; k0 += 64) {
        uint4 a0 = load8(xs, abase + k0,      axfl);
        uint4 a1 = load8(xs, abase + k0 + 8,  axfl);
        uint4 a2 = load8(xs, abase + k0 + 16, axfl);
        uint4 a3 = load8(xs, abase + k0 + 24, axfl);
        *(uint4*)&As[arow * LDA + acol]      = a0;
        *(uint4*)&As[arow * LDA + acol + 8]  = a1;
        *(uint4*)&As[arow * LDA + acol + 16] = a2;
        *(uint4*)&As[arow * LDA + acol + 24] = a3;
        if (wb) {
            const unsigned short* bp = (const unsigned short*)bsrc + bbT + k0;
            uint4 b0 = *(const uint4*)(bp);
            uint4 b1 = *(const uint4*)(bp + 8);
            uint4 b2 = *(const uint4*)(bp + 16);
            uint4 b3 = *(const uint4*)(bp + 24);
            *(uint4*)&bdst[bfr * LDA + bdc]      = b0;
            *(uint4*)&bdst[bfr * LDA + bdc + 8]  = b1;
            *(uint4*)&bdst[bfr * LDA + bdc + 16] = b2;
            *(uint4*)&bdst[bfr * LDA + bdc + 24] = b3;
        } else {
            uint4 r0 = load8(bsrc, bbS + (size_t)(bd0 + k0 + 0) * F_DIM, fl);
            uint4 r1 = load8(bsrc, bbS + (size_t)(bd0 + k0 + 1) * F_DIM, fl);
            uint4 r2 = load8(bsrc, bbS + (size_t)(bd0 + k0 + 2) * F_DIM, fl);
            uint4 r3 = load8(bsrc, bbS + (size_t)(bd0 + k0 + 3) * F_DIM, fl);
            const unsigned short* s0 = (const unsigned short*)&r0;
            const unsigned short* s1 = (const unsigned short*)&r1;
            const unsigned short* s2 = (const unsigned short*)&r2;
            const unsigned short* s3 = (const unsigned short*)&r3;
#pragma unroll
            for (int j = 0; j < 8; j++) {
                uint2 pk;
                pk.x = (unsigned)s0[j] | ((unsigned)s1[j] << 16);
                pk.y = (unsigned)s2[j] | ((unsigned)s3[j] << 16);
                *(uint2*)&bdst[(bf0 + j) * LDA + bd0] = pk;   // transposed: [f][d]
            }
        }
        __syncthreads();
#pragma unroll
        for (int kk = 0; kk < 2; kk++) {
            int ko = kk * 32 + (lane >> 4) * 8;
            bf16_8 a0f = *(const bf16_8*)&As[(wv * 32 +      (lane & 15)) * LDA + ko];
            bf16_8 a1f = *(const bf16_8*)&As[(wv * 32 + 16 + (lane & 15)) * LDA + ko];
#pragma unroll
            for (int nn = 0; nn < 4; nn++) {
                bf16_8 b1 = *(const bf16_8*)&B1s[(nn * 16 + (lane & 15)) * LDA + ko];
                acc1[0][nn] = __builtin_amdgcn_mfma_f32_16x16x32_bf16(a0f, b1, acc1[0][nn], 0, 0, 0);
                acc1[1][nn] = __builtin_amdgcn_mfma_f32_16x16x32_bf16(a1f, b1, acc1[1][nn], 0, 0, 0);
                bf16_8 b3 = *(const bf16_8*)&B3s[(nn * 16 + (lane & 15)) * LDA + ko];
                acc3[0][nn] = __builtin_amdgcn_mfma_f32_16x16x32_bf16(a0f, b3, acc3[0][nn], 0, 0, 0);
                acc3[1][nn] = __builtin_amdgcn_mfma_f32_16x16x32_bf16(a1f, b3, acc3[1][nn], 0, 0, 0);
            }
        }
        __syncthreads();
    }
#pragma unroll
    for (int m = 0; m < 2; m++)
#pragma unroll
    for (int reg = 0; reg < 4; reg++) {
        int r = wv * 32 + m * 16 + (lane >> 4) * 4 + reg;
        if (r < rows) {
            int hr = iclamp(lbase_r + r, 0, hrows - 1);
            size_t rowoff = (size_t)hr * F_DIM + f0;
#pragma unroll
            for (int nn = 0; nn < 4; nn++) {
                float g = acc1[m][nn][reg], u = acc3[m][nn][reg];
                float h = (g / (1.f + __expf(-g))) * u;
                H[rowoff + nn * 16 + (lane & 15)] = f2bf(h);
            }
        }
    }
}

// ---------------- GEMM2: out[t] += (H * W2) * gate_w  (f32 atomicAdd) ----------------
// wb=1: b2p is bf16 pre-transposed [E][D][F].  wb=0: original [E][F][D] (fl dtype).
__global__ __launch_bounds__(256) void k_gemm2(const unsigned short* __restrict__ H,
                                               const void* __restrict__ b2p,
                                               const int*  __restrict__ meta,
                                               const int4* __restrict__ tiles,
                                               const int*  __restrict__ pt,
                                               const float* __restrict__ pw,
                                               float* __restrict__ out,
                                               int cbase, int clen, int wb, int hslop)
{
    __shared__ unsigned short As[128 * LDA];
    __shared__ unsigned short Bs[64 * LDA];
    int nt = iclamp(meta[25], 0, MAX_TILES);
    if ((int)blockIdx.x >= nt) return;
    int4 td = tiles[blockIdx.x];
    if (td.x < cbase || td.x >= cbase + clen) return;
    int fl   = meta[26];
    int base = iclamp(td.x, 0, NPAIR-1);
    int e    = iclamp(td.y, 0, E_NUM-1);
    int rows = iclamp(td.z, 1, 128);
    if (base + rows > NPAIR) rows = NPAIR - base;
    int hrows = clen + hslop;
    int lbase_r = base - cbase;
    int n0 = blockIdx.y * 64;
    int tid = threadIdx.x, lane = tid & 63, wv = tid >> 6;

    // A staging from H (bf16): 2 threads/row, 32 elems each
    int arow = tid >> 1;
    int acol = (tid & 1) * 32;
    int ar   = arow < rows ? arow : rows - 1;
    int ahr  = iclamp(lbase_r + ar, 0, hrows - 1);
    const unsigned short* aptr = H + (size_t)ahr * F_DIM + acol;

    // B staging (fast, pre-transposed [E][D][F]): tid<128, 2 threads/d-row
    int bu = tid & 127;
    int bdr = bu >> 1;
    int bfc = (bu & 1) * 32;
    size_t bbT = (size_t)e * D_DIM * F_DIM + (size_t)(n0 + bdr) * F_DIM + (size_t)bfc;
    // B staging (slow, original [E][F][D]): 4 f-rows x 8 d each, transpose scatter
    int bf0 = (bu & 15) * 4;
    int bd0 = (bu >> 4) * 8;
    size_t bbS = (size_t)e * F_DIM * D_DIM + (size_t)(n0 + bd0);

    f32_4 acc[2][4];
#pragma unroll
    for (int m = 0; m < 2; m++)
#pragma unroll
        for (int nn = 0; nn < 4; nn++) acc[m][nn] = 0.f;

    for (int k0 = 0; k0 < F_DIM; k0 += 64) {
        uint4 a0 = *(const uint4*)(aptr + k0);
        uint4 a1 = *(const uint4*)(aptr + k0 + 8);
        uint4 a2 = *(const uint4*)(aptr + k0 + 16);
        uint4 a3 = *(const uint4*)(aptr + k0 + 24);
        *(uint4*)&As[arow * LDA + acol]      = a0;
        *(uint4*)&As[arow * LDA + acol + 8]  = a1;
        *(uint4*)&As[arow * LDA + acol + 16] = a2;
        *(uint4*)&As[arow * LDA + acol + 24] = a3;
        if (tid < 128) {
            if (wb) {
                const unsigned short* bp = (const unsigned short*)b2p + bbT + k0;
                uint4 b0 = *(const uint4*)(bp);
                uint4 b1 = *(const uint4*)(bp + 8);
                uint4 b2 = *(const uint4*)(bp + 16);
                uint4 b3 = *(const uint4*)(bp + 24);
                *(uint4*)&Bs[bdr * LDA + bfc]      = b0;
                *(uint4*)&Bs[bdr * LDA + bfc + 8]  = b1;
                *(uint4*)&Bs[bdr * LDA + bfc + 16] = b2;
                *(uint4*)&Bs[bdr * LDA + bfc + 24] = b3;
            } else {
                uint4 r0 = load8(b2p, bbS + (size_t)(bf0 + k0 + 0) * D_DIM, fl);
                uint4 r1 = load8(b2p, bbS + (size_t)(bf0 + k0 + 1) * D_DIM, fl);
                uint4 r2 = load8(b2p, bbS + (size_t)(bf0 + k0 + 2) * D_DIM, fl);
                uint4 r3 = load8(b2p, bbS + (size_t)(bf0 + k0 + 3) * D_DIM, fl);
                const unsigned short* s0 = (const unsigned short*)&r0;
                const unsigned short* s1 = (const unsigned short*)&r1;
                const unsigned short* s2 = (const unsigned short*)&r2;
                const unsigned short* s3 = (const unsigned short*)&r3;
#pragma unroll
                for (int j = 0; j < 8; j++) {
                    uint2 pk;
                    pk.x = (unsigned)s0[j] | ((unsigned)s1[j] << 16);
                    pk.y = (unsigned)s2[j] | ((unsigned)s3[j] << 16);
                    *(uint2*)&Bs[(bd0 + j) * LDA + bf0] = pk;   // [d][f]
                }
            }
        }
        __syncthreads();
#pragma unroll
        for (int kk = 0; kk < 2; kk++) {
            int ko = kk * 32 + (lane >> 4) * 8;
            bf16_8 a0f = *(const bf16_8*)&As[(wv * 32 +      (lane & 15)) * LDA + ko];
            bf16_8 a1f = *(const bf16_8*)&As[(wv * 32 + 16 + (lane & 15)) * LDA + ko];
#pragma unroll
            for (int nn = 0; nn < 4; nn++) {
                bf16_8 b = *(const bf16_8*)&Bs[(nn * 16 + (lane & 15)) * LDA + ko];
                acc[0][nn] = __builtin_amdgcn_mfma_f32_16x16x32_bf16(a0f, b, acc[0][nn], 0, 0, 0);
                acc[1][nn] = __builtin_amdgcn_mfma_f32_16x16x32_bf16(a1f, b, acc[1][nn], 0, 0, 0);
            }
        }
        __syncthreads();
    }
    // epilogue: f32 atomic accumulate (C/D: col=lane&15, row=(lane>>4)*4+reg)
#pragma unroll
    for (int m = 0; m < 2; m++)
#pragma unroll
    for (int reg = 0; reg < 4; reg++) {
        int r = wv * 32 + m * 16 + (lane >> 4) * 4 + reg;
        if (r < rows) {
            int idx = iclamp(base + r, 0, NPAIR-1);
            float w = pw[idx];
            int   t = iclamp(pt[idx], 0, T_TOK-1);
#pragma unroll
            for (int nn = 0; nn < 4; nn++) {
                float v = acc[m][nn][reg] * w;
                atomicAdd(&out[(size_t)t * D_DIM + (size_t)(n0 + nn * 16 + (lane & 15))], v);
            }
        }
    }
}

extern "C" void kernel_launch(void* const* d_in, const int* in_sizes, int n_in,
                              void* d_out, int out_size, void* d_ws, size_t ws_size,
                              hipStream_t stream)
{
    if (!d_in || n_in < 5 || !d_out || !d_ws) return;
    const void* x  = d_in[0];  // [T, D] f32
    const void* wg = d_in[1];  // [D, E] f32
    const void* w1 = d_in[2];  // [E, D, F] f32
    const void* w3 = d_in[3];  // [E, D, F] f32
    const void* w2 = d_in[4];  // [E, F, D] f32
    char* ws = (char*)d_ws;
    float* out = (float*)d_out;

    // out is poisoned each call; we accumulate into it -> zero all 32 MB
    // (out_size is the f32 element count == T_TOK*D_DIM; extent is compile-time fixed)
    k_zero_out<<<(T_TOK * D_DIM) / (256 * 4), 256, 0, stream>>>((uint4*)out);

    const size_t xb_sz  = (size_t)T_TOK * D_DIM * 2;                 // 16 MB
    const size_t epp    = (size_t)E_NUM * D_DIM * F_DIM * 2;         // 32 MB per weight tensor
    const size_t wb_sz  = 3 * epp;                                   // 96 MB
    static const int cand[9] = {1, 2, 4, 8, 16, 32, 64, 128, 256};

    // tier selection: {Wb+Xb} > {Xb} > {raw} at bmStep=128; last resort bmStep=64 raw
    int bmStep = 128, NC = 256, useWb = 0, useXb = 0, found = 0;
    const int tw[3] = {1, 0, 0};
    const int tx[3] = {1, 1, 0};
    for (int ti = 0; ti < 3 && !found; ti++)
        for (int i = 0; i < 9 && !found; i++) {
            size_t hrows = (size_t)(NPAIR / cand[i]) + 128;
            size_t need = DYN_OFF + (tx[ti] ? xb_sz : 0) + (tw[ti] ? wb_sz : 0)
                        + hrows * F_DIM * 2;
            if (need <= ws_size) { NC = cand[i]; useWb = tw[ti]; useXb = tx[ti]; found = 1; }
        }
    if (!found) {
        bmStep = 64;
        for (int i = 0; i < 9 && !found; i++) {
            size_t hrows = (size_t)(NPAIR / cand[i]) + 64;
            if (DYN_OFF + hrows * F_DIM * 2 <= ws_size) { NC = cand[i]; found = 1; }
        }
        if (!found) return;   // diagnostic guard (would show absmax==2.5625)
    }
    int CH = NPAIR / NC;

    int*   meta  = (int*)(ws + META_OFF);
    int4*  tiles = (int4*)(ws + TILE_OFF);
    int*   ridx  = (int*)(ws + RIDX_OFF);
    float* rw    = (float*)(ws + RW_OFF);
    int*   pt    = (int*)(ws + PT_OFF);
    float* pw    = (float*)(ws + PW_OFF);
    size_t off = DYN_OFF;
    unsigned short* Xb = (unsigned short*)(ws + off); if (useXb) off += xb_sz;
    unsigned short* Wb1 = (unsigned short*)(ws + off);
    unsigned short* Wb3 = Wb1 + epp / 2;
    unsigned short* Wb2 = Wb3 + epp / 2;
    if (useWb) off += wb_sz;
    unsigned short* H = (unsigned short*)(ws + off);

    const void* xs  = useXb ? (const void*)Xb : x;
    const void* b1p = useWb ? (const void*)Wb1 : w1;
    const void* b3p = useWb ? (const void*)Wb3 : w3;
    const void* b2p = useWb ? (const void*)Wb2 : w2;

    k_zero  <<<4, 256, 0, stream>>>(meta);
    k_dtype <<<1, 64, 0, stream>>>((const unsigned*)x, meta);
    if (useXb) k_cvt_x<<<(T_TOK * D_DIM) / 2048, 256, 0, stream>>>(x, Xb, meta);
    if (useWb) {
        // W1,W3: [E][D][F] -> [E][F][D];  W2: [E][F][D] -> [E][D][F]
        k_cvt_t<<<E_NUM * (D_DIM/64) * (F_DIM/64), 256, 0, stream>>>(w1, Wb1, meta, D_DIM, F_DIM);
        k_cvt_t<<<E_NUM * (D_DIM/64) * (F_DIM/64), 256, 0, stream>>>(w3, Wb3, meta, D_DIM, F_DIM);
        k_cvt_t<<<E_NUM * (F_DIM/64) * (D_DIM/64), 256, 0, stream>>>(w2, Wb2, meta, F_DIM, D_DIM);
    }
    k_router <<<T_TOK / 4, 256, 0, stream>>>(x, wg, meta, ridx, rw);
    k_setup  <<<1, 64, 0, stream>>>(meta, tiles, bmStep);
    k_scatter<<<T_TOK / 256, 256, 0, stream>>>(ridx, rw, meta, pt, pw);
    for (int c = 0; c < NC; c++) {
        k_gemm1<<<dim3(MAX_TILES, F_DIM / 64), 256, 0, stream>>>(
            xs, b1p, b3p, meta, tiles, pt, H, c * CH, CH, useXb, useWb, bmStep);
        k_gemm2<<<dim3(MAX_TILES, D_DIM / 64), 256, 0, stream>>>(
            H, b2p, meta, tiles, pt, pw, out, c * CH, CH, useWb, bmStep);
    }
}